// Round 1
// baseline (279.848 us; speedup 1.0000x reference)
//
#include <hip/hip_runtime.h>
#include <hip/hip_bf16.h>

// LocalBlock: LN1 -> qkv GEMM -> multi-dilate local attn -> +xn -> proj GEMM -> +x
//            -> LN2 -> fc1+gelu -> fc2 -> +x -> transpose out
// B=8 C=384 H=W=56 N=25088 NH=12 hd=32 dils=(1,2,3) HID=1536

#define B_   8
#define C_   384
#define W_   56
#define HW_  3136
#define N_   25088
#define HD_  32
#define HID_ 1536
#define C3_  1152

typedef __attribute__((ext_vector_type(8))) short short8v;
typedef __attribute__((ext_vector_type(4))) float f32x4;

__device__ __forceinline__ float bf2f(unsigned short u) {
  union { float f; unsigned u; } c; c.u = ((unsigned)u) << 16; return c.f;
}
__device__ __forceinline__ unsigned short f2bf(float f) {
  unsigned u = __float_as_uint(f);
  u = (u + 0x7FFFu + ((u >> 16) & 1u)) >> 16;
  return (unsigned short)u;
}

// ---------------- weight fp32 -> bf16 ----------------
__global__ void cvt_weights(const float* __restrict__ qw, const float* __restrict__ pw,
                            const float* __restrict__ f1, const float* __restrict__ f2,
                            unsigned short* __restrict__ o) {
  int i = blockIdx.x * 256 + threadIdx.x;
  if (i < 442368)        o[i] = f2bf(qw[i]);
  else if (i < 589824)   o[i] = f2bf(pw[i - 442368]);
  else if (i < 1179648)  o[i] = f2bf(f1[i - 589824]);
  else if (i < 1769472)  o[i] = f2bf(f2[i - 1179648]);
}

// ---------------- x [B,C,HW] -> xp [N,C] (fp32) ----------------
__global__ __launch_bounds__(256)
void transpose_in(const float* __restrict__ x, float* __restrict__ xp) {
  __shared__ float t[32][33];
  const int tx = threadIdx.x, ty = threadIdx.y;
  const int hw0 = blockIdx.x * 32, c0 = blockIdx.y * 32, bz = blockIdx.z;
  const float* xb = x + (size_t)bz * C_ * HW_;
#pragma unroll
  for (int j = 0; j < 4; ++j)
    t[ty + j * 8][tx] = xb[(size_t)(c0 + ty + j * 8) * HW_ + hw0 + tx];
  __syncthreads();
  float* xpb = xp + ((size_t)bz * HW_ + hw0) * C_;
#pragma unroll
  for (int j = 0; j < 4; ++j)
    xpb[(size_t)(ty + j * 8) * C_ + c0 + tx] = t[tx][ty + j * 8];
}

// ---------------- row LayerNorm (fp32 in) -> bf16 out ----------------
__global__ __launch_bounds__(256)
void ln_rows(const float* __restrict__ in, unsigned short* __restrict__ outb,
             const float* __restrict__ g, const float* __restrict__ bb) {
  const int row = blockIdx.x * 4 + (threadIdx.x >> 6);
  const int lane = threadIdx.x & 63;
  const float* rp = in + (size_t)row * C_;
  float v[6]; float s = 0.f, ss = 0.f;
#pragma unroll
  for (int j = 0; j < 6; ++j) { v[j] = rp[lane + j * 64]; s += v[j]; ss += v[j] * v[j]; }
#pragma unroll
  for (int off = 32; off; off >>= 1) { s += __shfl_xor(s, off); ss += __shfl_xor(ss, off); }
  const float mean = s * (1.f / 384.f);
  const float var = ss * (1.f / 384.f) - mean * mean;
  const float rstd = rsqrtf(var + 1e-5f);
  unsigned short* op = outb + (size_t)row * C_;
#pragma unroll
  for (int j = 0; j < 6; ++j) {
    const int c = lane + j * 64;
    op[c] = f2bf((v[j] - mean) * rstd * g[c] + bb[c]);
  }
}

// ---------------- MFMA GEMM: out[M,Nn] = A[M,K](bf16) @ W[Nn,K]^T(bf16) ----------------
// MODE 0: -> bf16 out (qkv)
// MODE 1: -> fp32 out = resid + val + bias (proj, in-place on resid)
// MODE 2: -> bf16 out = gelu_exact(val + bias) (fc1)
// MODE 3: -> fp32 d_out[B,C,HW] = resid + val + bias, transposed store (fc2)
template <int MODE>
__global__ __launch_bounds__(256, 2)
void gemm_bt(const unsigned short* __restrict__ A, const unsigned short* __restrict__ Bw,
             const float* __restrict__ bias, const float* __restrict__ resid,
             void* __restrict__ outp, int Nn, int K) {
  __shared__ unsigned short lds[2][2][128 * 32];
  const int tid = threadIdx.x;
  const int lane = tid & 63, wv = tid >> 6;
  const int wm = wv >> 1, wn = wv & 1;
  const int m0 = blockIdx.x * 128, n0 = blockIdx.y * 128;

  const int srow = wv * 32 + (lane >> 2);   // staging row within 128-tile
  const int scol = (lane & 3) * 8;          // staging col (bf16 elems)

  f32x4 acc[4][4] = {};

  auto stage = [&](int buf, int kt) {
    const int k0 = kt * 32;
    const unsigned short* ga0 = A + (size_t)(m0 + srow) * K + k0 + scol;
    const unsigned short* gb0 = Bw + (size_t)(n0 + srow) * K + k0 + scol;
    unsigned short* la = &lds[buf][0][srow * 32 + scol];
    unsigned short* lb = &lds[buf][1][srow * 32 + scol];
    __builtin_amdgcn_global_load_lds((const __attribute__((address_space(1))) void*)ga0,
                                     (__attribute__((address_space(3))) void*)la, 16, 0, 0);
    __builtin_amdgcn_global_load_lds((const __attribute__((address_space(1))) void*)(ga0 + 16 * K),
                                     (__attribute__((address_space(3))) void*)(la + 16 * 32), 16, 0, 0);
    __builtin_amdgcn_global_load_lds((const __attribute__((address_space(1))) void*)gb0,
                                     (__attribute__((address_space(3))) void*)lb, 16, 0, 0);
    __builtin_amdgcn_global_load_lds((const __attribute__((address_space(1))) void*)(gb0 + 16 * K),
                                     (__attribute__((address_space(3))) void*)(lb + 16 * 32), 16, 0, 0);
  };

  const int KT = K >> 5;
  stage(0, 0);
  __syncthreads();
  int buf = 0;
  const int rA = lane & 15;
  const int kg = (lane >> 4) * 8;
  for (int kt = 0; kt < KT; ++kt) {
    if (kt + 1 < KT) stage(buf ^ 1, kt + 1);
    short8v af[4], bfr[4];
#pragma unroll
    for (int mt = 0; mt < 4; ++mt)
      af[mt] = *(const short8v*)&lds[buf][0][(wm * 64 + mt * 16 + rA) * 32 + kg];
#pragma unroll
    for (int nt = 0; nt < 4; ++nt)
      bfr[nt] = *(const short8v*)&lds[buf][1][(wn * 64 + nt * 16 + rA) * 32 + kg];
#pragma unroll
    for (int mt = 0; mt < 4; ++mt)
#pragma unroll
      for (int nt = 0; nt < 4; ++nt)
        acc[mt][nt] = __builtin_amdgcn_mfma_f32_16x16x32_bf16(af[mt], bfr[nt], acc[mt][nt], 0, 0, 0);
    __syncthreads();
    buf ^= 1;
  }

  // C/D layout: col = lane&15, row = (lane>>4)*4 + j  [measured, guide §3]
  const int co = lane & 15;
  const int r4 = (lane >> 4) * 4;
#pragma unroll
  for (int mt = 0; mt < 4; ++mt) {
    const int nbase = m0 + wm * 64 + mt * 16 + r4;
#pragma unroll
    for (int nt = 0; nt < 4; ++nt) {
      const int o = n0 + wn * 64 + nt * 16 + co;
#pragma unroll
      for (int j = 0; j < 4; ++j) {
        const int nn = nbase + j;
        const float v = acc[mt][nt][j];
        if (MODE == 0) {
          ((unsigned short*)outp)[(size_t)nn * C3_ + o] = f2bf(v);
        } else if (MODE == 1) {
          const size_t ix = (size_t)nn * C_ + o;
          ((float*)outp)[ix] = resid[ix] + v + bias[o];
        } else if (MODE == 2) {
          const float xv = v + bias[o];
          const float gl = 0.5f * xv * (1.f + erff(xv * 0.70710678118f));
          ((unsigned short*)outp)[(size_t)nn * HID_ + o] = f2bf(gl);
        } else {
          const float rv = resid[(size_t)nn * C_ + o] + v + bias[o];
          const int bb = nn / HW_, hw = nn - bb * HW_;
          ((float*)outp)[((size_t)bb * C_ + o) * HW_ + hw] = rv;
        }
      }
    }
  }
}

// ---------------- multi-dilate local attention ----------------
// thread <-> (n, r) with r = dil_idx*4 + head (12 per position)
// qkv [N,1152] bf16: q at r*32, k at 384 + r*32, v at 768 + r*32
// out: abuf[n*384 + r*32 + c] = attn_out + xn  (bf16)
__global__ __launch_bounds__(256)
void attn_kernel(const unsigned short* __restrict__ qkv,
                 const unsigned short* __restrict__ xn,
                 unsigned short* __restrict__ aout) {
  const int gid = blockIdx.x * 256 + threadIdx.x;
  const int n = gid / 12;
  const int r = gid - n * 12;
  const int dil = (r >> 2) + 1;
  const int b = n / HW_;
  const int hw = n - b * HW_;
  const int h = hw / W_;
  const int w = hw - h * W_;

  const size_t base = (size_t)n * C3_ + (size_t)r * HD_;
  float q[32];
  {
    const short8v* vp = (const short8v*)(qkv + base);
#pragma unroll
    for (int c8 = 0; c8 < 4; ++c8) {
      short8v v = vp[c8];
#pragma unroll
      for (int e = 0; e < 8; ++e) q[c8 * 8 + e] = bf2f((unsigned short)v[e]);
    }
  }

  float logit[9];
#pragma unroll
  for (int ti = 0; ti < 3; ++ti)
#pragma unroll
    for (int tj = 0; tj < 3; ++tj) {
      const int t = ti * 3 + tj;
      const int hn = h + (ti - 1) * dil, wn = w + (tj - 1) * dil;
      if ((unsigned)hn < 56u && (unsigned)wn < 56u) {
        const int nb = n + (ti - 1) * dil * W_ + (tj - 1) * dil;
        const short8v* kp = (const short8v*)(qkv + (size_t)nb * C3_ + C_ + (size_t)r * HD_);
        float dot = 0.f;
#pragma unroll
        for (int c8 = 0; c8 < 4; ++c8) {
          short8v v = kp[c8];
#pragma unroll
          for (int e = 0; e < 8; ++e) dot += q[c8 * 8 + e] * bf2f((unsigned short)v[e]);
        }
        logit[t] = dot * 0.17677669529663688f;  // 32^-0.5
      } else {
        logit[t] = 0.f;  // zero-padded taps participate with logit 0
      }
    }

  float mx = logit[0];
#pragma unroll
  for (int t = 1; t < 9; ++t) mx = fmaxf(mx, logit[t]);
  float wgt[9]; float se = 0.f;
#pragma unroll
  for (int t = 0; t < 9; ++t) { wgt[t] = __expf(logit[t] - mx); se += wgt[t]; }
  const float inv = 1.f / se;

  float acc[32];
#pragma unroll
  for (int c = 0; c < 32; ++c) acc[c] = 0.f;
#pragma unroll
  for (int ti = 0; ti < 3; ++ti)
#pragma unroll
    for (int tj = 0; tj < 3; ++tj) {
      const int t = ti * 3 + tj;
      const int hn = h + (ti - 1) * dil, wn = w + (tj - 1) * dil;
      if ((unsigned)hn < 56u && (unsigned)wn < 56u) {
        const int nb = n + (ti - 1) * dil * W_ + (tj - 1) * dil;
        const short8v* vp = (const short8v*)(qkv + (size_t)nb * C3_ + 2 * C_ + (size_t)r * HD_);
        const float wt = wgt[t];
#pragma unroll
        for (int c8 = 0; c8 < 4; ++c8) {
          short8v v = vp[c8];
#pragma unroll
          for (int e = 0; e < 8; ++e) acc[c8 * 8 + e] += wt * bf2f((unsigned short)v[e]);
        }
      }
    }

  const size_t obase = (size_t)n * C_ + (size_t)r * HD_;
  const short8v* xv = (const short8v*)(xn + obase);
  short8v ov[4];
#pragma unroll
  for (int c8 = 0; c8 < 4; ++c8) {
    short8v v = xv[c8];
#pragma unroll
    for (int e = 0; e < 8; ++e)
      ov[c8][e] = (short)f2bf(acc[c8 * 8 + e] * inv + bf2f((unsigned short)v[e]));
  }
  short8v* op = (short8v*)(aout + obase);
#pragma unroll
  for (int c8 = 0; c8 < 4; ++c8) op[c8] = ov[c8];
}

extern "C" void kernel_launch(void* const* d_in, const int* in_sizes, int n_in,
                              void* d_out, int out_size, void* d_ws, size_t ws_size,
                              hipStream_t stream) {
  const float* x = (const float*)d_in[0];
  const float* qkv_w = (const float*)d_in[1];
  const float* proj_w = (const float*)d_in[2];
  const float* proj_b = (const float*)d_in[3];
  const float* n1_g = (const float*)d_in[4];
  const float* n1_b = (const float*)d_in[5];
  const float* n2_g = (const float*)d_in[6];
  const float* n2_b = (const float*)d_in[7];
  const float* fc1_w = (const float*)d_in[8];
  const float* fc1_b = (const float*)d_in[9];
  const float* fc2_w = (const float*)d_in[10];
  const float* fc2_b = (const float*)d_in[11];

  char* ws = (char*)d_ws;
  float* xp = (float*)ws;                                        // 38,535,168 B  [N,C] f32
  unsigned short* xn = (unsigned short*)(ws + 38535168);         // 19,267,584 B  [N,C] bf16 (xn, later x2n)
  unsigned short* qkvb = (unsigned short*)(ws + 57802752);       // 57,802,752 B  [N,1152] bf16
  unsigned short* abuf = (unsigned short*)(ws + 115605504);      // 19,267,584 B  [N,C] bf16
  unsigned short* hbuf = qkvb;                                   // 77,070,336 B  [N,1536] bf16 (reuse qkv+abuf)
  unsigned short* wq = (unsigned short*)(ws + 134873088);
  unsigned short* wp = wq + 442368;
  unsigned short* wf1 = wp + 147456;
  unsigned short* wf2 = wf1 + 589824;

  cvt_weights<<<6912, 256, 0, stream>>>(qkv_w, proj_w, fc1_w, fc2_w, wq);
  transpose_in<<<dim3(98, 12, 8), dim3(32, 8), 0, stream>>>(x, xp);
  ln_rows<<<6272, 256, 0, stream>>>(xp, xn, n1_g, n1_b);
  gemm_bt<0><<<dim3(196, 9), 256, 0, stream>>>(xn, wq, nullptr, nullptr, qkvb, C3_, C_);
  attn_kernel<<<1176, 256, 0, stream>>>(qkvb, xn, abuf);
  gemm_bt<1><<<dim3(196, 3), 256, 0, stream>>>(abuf, wp, proj_b, xp, xp, C_, C_);
  ln_rows<<<6272, 256, 0, stream>>>(xp, xn, n2_g, n2_b);
  gemm_bt<2><<<dim3(196, 12), 256, 0, stream>>>(xn, wf1, fc1_b, nullptr, hbuf, HID_, C_);
  gemm_bt<3><<<dim3(196, 3), 256, 0, stream>>>(hbuf, wf2, fc2_b, xp, d_out, C_, HID_);
}

// Round 2
// 279.325 us; speedup vs baseline: 1.0019x; 1.0019x over previous
//
#include <hip/hip_runtime.h>
#include <hip/hip_bf16.h>

// LocalBlock: LN1 -> qkv GEMM -> multi-dilate local attn -> +xn -> proj GEMM -> +x
//            -> LN2 -> fc1+gelu -> fc2 -> +x -> transpose out
// B=8 C=384 H=W=56 N=25088 NH=12 hd=32 dils=(1,2,3) HID=1536

#define B_   8
#define C_   384
#define W_   56
#define HW_  3136
#define N_   25088
#define HD_  32
#define HID_ 1536
#define C3_  1152

typedef __attribute__((ext_vector_type(8))) short short8v;
typedef __attribute__((ext_vector_type(4))) float f32x4;

__device__ __forceinline__ float bf2f(unsigned short u) {
  union { float f; unsigned u; } c; c.u = ((unsigned)u) << 16; return c.f;
}
__device__ __forceinline__ unsigned short f2bf(float f) {
  unsigned u = __float_as_uint(f);
  u = (u + 0x7FFFu + ((u >> 16) & 1u)) >> 16;
  return (unsigned short)u;
}

// ---------------- weight fp32 -> bf16 ----------------
__global__ void cvt_weights(const float* __restrict__ qw, const float* __restrict__ pw,
                            const float* __restrict__ f1, const float* __restrict__ f2,
                            unsigned short* __restrict__ o) {
  int i = blockIdx.x * 256 + threadIdx.x;
  if (i < 442368)        o[i] = f2bf(qw[i]);
  else if (i < 589824)   o[i] = f2bf(pw[i - 442368]);
  else if (i < 1179648)  o[i] = f2bf(f1[i - 589824]);
  else if (i < 1769472)  o[i] = f2bf(f2[i - 1179648]);
}

// ---------------- x [B,C,HW] -> xp [N,C] (fp32) ----------------
__global__ __launch_bounds__(256)
void transpose_in(const float* __restrict__ x, float* __restrict__ xp) {
  __shared__ float t[32][33];
  const int tx = threadIdx.x, ty = threadIdx.y;
  const int hw0 = blockIdx.x * 32, c0 = blockIdx.y * 32, bz = blockIdx.z;
  const float* xb = x + (size_t)bz * C_ * HW_;
#pragma unroll
  for (int j = 0; j < 4; ++j)
    t[ty + j * 8][tx] = xb[(size_t)(c0 + ty + j * 8) * HW_ + hw0 + tx];
  __syncthreads();
  float* xpb = xp + ((size_t)bz * HW_ + hw0) * C_;
#pragma unroll
  for (int j = 0; j < 4; ++j)
    xpb[(size_t)(ty + j * 8) * C_ + c0 + tx] = t[tx][ty + j * 8];
}

// ---------------- row LayerNorm (fp32 in) -> bf16 out ----------------
__global__ __launch_bounds__(256)
void ln_rows(const float* __restrict__ in, unsigned short* __restrict__ outb,
             const float* __restrict__ g, const float* __restrict__ bb) {
  const int row = blockIdx.x * 4 + (threadIdx.x >> 6);
  const int lane = threadIdx.x & 63;
  const float* rp = in + (size_t)row * C_;
  float v[6]; float s = 0.f, ss = 0.f;
#pragma unroll
  for (int j = 0; j < 6; ++j) { v[j] = rp[lane + j * 64]; s += v[j]; ss += v[j] * v[j]; }
#pragma unroll
  for (int off = 32; off; off >>= 1) { s += __shfl_xor(s, off); ss += __shfl_xor(ss, off); }
  const float mean = s * (1.f / 384.f);
  const float var = ss * (1.f / 384.f) - mean * mean;
  const float rstd = rsqrtf(var + 1e-5f);
  unsigned short* op = outb + (size_t)row * C_;
#pragma unroll
  for (int j = 0; j < 6; ++j) {
    const int c = lane + j * 64;
    op[c] = f2bf((v[j] - mean) * rstd * g[c] + bb[c]);
  }
}

// ---------------- MFMA GEMM: out[M,Nn] = A[M,K](bf16) @ W[Nn,K]^T(bf16) ----------------
// BM=BN=128, BK=32, 8 waves (2M x 4N, wave tile 64x32), 4 LDS slots, prefetch 3 ahead,
// counted vmcnt (4/2/0), raw s_barrier, XOR swizzle (16B slot ^= row&3) on LDS.
// MODE 0: -> bf16 out (qkv / generic)
// MODE 1: -> fp32 out = resid + val + bias (proj, in-place on resid)
// MODE 2: -> bf16 out = gelu_exact(val + bias) (fc1)
// MODE 3: -> fp32 d_out[B,C,HW] = resid + val + bias, LDS-transposed coalesced store (fc2)
template <int MODE>
__global__ __launch_bounds__(512, 4)
void gemm128(const unsigned short* __restrict__ A, const unsigned short* __restrict__ Bw,
             const float* __restrict__ bias, const float* resid,
             void* __restrict__ outp, int Nout, int K) {
  __shared__ unsigned short lds[4][8192];   // slot: A[128][32] + B[128][32], swizzled
  const int tid = threadIdx.x;
  const int l = tid & 63, wv = tid >> 6;
  const int wm = wv >> 2, wn = wv & 3;
  const int m0 = blockIdx.y * 128, n0 = blockIdx.x * 128;

  // staging: wave wv covers rows [wv*16, wv*16+16) of A-tile and of B-tile.
  // LDS chunk is linear 1024B (lane*16); source col pre-swizzled (slot ^= row&3).
  const int rl = l >> 2;                         // row within chunk 0..15
  const int cs = (((l & 3) ^ (rl & 3)) << 3);    // source col (elems), inverse swizzle
  const unsigned short* gA = A + (size_t)(m0 + wv * 16 + rl) * K + cs;
  const unsigned short* gB = Bw + (size_t)(n0 + wv * 16 + rl) * K + cs;
  const int ldst = wv * 512 + l * 8;             // ushort index in slot

  auto stage = [&](int kt) {
    const int s = kt & 3;
    const unsigned short* a = gA + kt * 32;
    const unsigned short* b = gB + kt * 32;
    __builtin_amdgcn_global_load_lds((const __attribute__((address_space(1))) void*)a,
        (__attribute__((address_space(3))) void*)&lds[s][ldst], 16, 0, 0);
    __builtin_amdgcn_global_load_lds((const __attribute__((address_space(1))) void*)b,
        (__attribute__((address_space(3))) void*)&lds[s][4096 + ldst], 16, 0, 0);
  };

  const int KT = K >> 5;     // 12 or 48, always >= 4
  stage(0); stage(1); stage(2);

  // fragment read coords (read-side swizzle; rows differ by mult of 4 -> swz const)
  const int fr = l & 15, g = l >> 4;
  const int swz = (g << 3) ^ ((fr & 3) << 3);
  const int aoff = (wm * 64 + fr) * 32 + swz;            // + mt*512
  const int boff = 4096 + (wn * 32 + fr) * 32 + swz;     // + nt*512

  f32x4 acc[4][2] = {};

  for (int t = 0; t < KT; ++t) {
    const int rem = KT - t;
    if (rem > 2)       asm volatile("s_waitcnt vmcnt(4)" ::: "memory");
    else if (rem == 2) asm volatile("s_waitcnt vmcnt(2)" ::: "memory");
    else               asm volatile("s_waitcnt vmcnt(0)" ::: "memory");
    __builtin_amdgcn_sched_barrier(0);
    __builtin_amdgcn_s_barrier();
    __builtin_amdgcn_sched_barrier(0);
    if (t + 3 < KT) stage(t + 3);   // slot (t+3)&3 was freed at end of iter t-1
    const unsigned short* sl = lds[t & 3];
    short8v af[4], bf[2];
#pragma unroll
    for (int mt = 0; mt < 4; ++mt) af[mt] = *(const short8v*)&sl[aoff + mt * 512];
#pragma unroll
    for (int nt = 0; nt < 2; ++nt) bf[nt] = *(const short8v*)&sl[boff + nt * 512];
#pragma unroll
    for (int mt = 0; mt < 4; ++mt)
#pragma unroll
      for (int nt = 0; nt < 2; ++nt)
        acc[mt][nt] = __builtin_amdgcn_mfma_f32_16x16x32_bf16(af[mt], bf[nt], acc[mt][nt], 0, 0, 0);
    __builtin_amdgcn_sched_barrier(0);
    asm volatile("s_waitcnt lgkmcnt(0)" ::: "memory");
    __builtin_amdgcn_sched_barrier(0);
    __builtin_amdgcn_s_barrier();
    __builtin_amdgcn_sched_barrier(0);
  }

  // C/D layout: col = lane&15 (fr), row = g*4 + j   [measured, guide §3]
  const int g4 = g * 4;
  if (MODE == 3) {
    // write acc (+bias+resid) into LDS as [col][row] f32 (swizzled), then coalesced store
    float* lf = (float*)lds;
#pragma unroll
    for (int mt = 0; mt < 4; ++mt) {
      const int nl = wm * 64 + mt * 16 + g4;   // local row base, multiple of 4
#pragma unroll
      for (int nt = 0; nt < 2; ++nt) {
        const int ol = wn * 32 + nt * 16 + fr; // local col
        const int og = n0 + ol;
        f32x4 v = acc[mt][nt];
        const float bo = bias[og];
#pragma unroll
        for (int j = 0; j < 4; ++j)
          v[j] = v[j] + bo + resid[(size_t)(m0 + nl + j) * C_ + og];
        *(f32x4*)&lf[ol * 128 + (((nl >> 2) ^ (ol & 7)) << 2)] = v;
      }
    }
    __syncthreads();
    float* out = (float*)outp;
    const int ol2 = tid >> 2, cb = tid & 3;
#pragma unroll
    for (int i = 0; i < 8; ++i) {
      const int c = cb + (i << 2);             // row-chunk 0..31
      f32x4 v = *(const f32x4*)&lf[ol2 * 128 + ((c ^ (ol2 & 7)) << 2)];
      const int ng = m0 + (c << 2);            // global row base (mult of 4, HW_%4==0)
      const int bb = ng / HW_;
      const int hw = ng - bb * HW_;
      *(f32x4*)&out[((size_t)bb * C_ + n0 + ol2) * HW_ + hw] = v;
    }
  } else {
#pragma unroll
    for (int mt = 0; mt < 4; ++mt) {
      const int nbase = m0 + wm * 64 + mt * 16 + g4;
#pragma unroll
      for (int nt = 0; nt < 2; ++nt) {
        const int o = n0 + wn * 32 + nt * 16 + fr;
#pragma unroll
        for (int j = 0; j < 4; ++j) {
          const int nn = nbase + j;
          const float v = acc[mt][nt][j];
          if (MODE == 0) {
            ((unsigned short*)outp)[(size_t)nn * Nout + o] = f2bf(v);
          } else if (MODE == 1) {
            const size_t ix = (size_t)nn * C_ + o;
            ((float*)outp)[ix] = resid[ix] + v + bias[o];
          } else {
            const float xv = v + bias[o];
            const float gl = 0.5f * xv * (1.f + erff(xv * 0.70710678118f));
            ((unsigned short*)outp)[(size_t)nn * Nout + o] = f2bf(gl);
          }
        }
      }
    }
  }
}

// ---------------- multi-dilate local attention ----------------
__global__ __launch_bounds__(256)
void attn_kernel(const unsigned short* __restrict__ qkv,
                 const unsigned short* __restrict__ xn,
                 unsigned short* __restrict__ aout) {
  const int gid = blockIdx.x * 256 + threadIdx.x;
  const int n = gid / 12;
  const int r = gid - n * 12;
  const int dil = (r >> 2) + 1;
  const int b = n / HW_;
  const int hw = n - b * HW_;
  const int h = hw / W_;
  const int w = hw - h * W_;

  const size_t base = (size_t)n * C3_ + (size_t)r * HD_;
  float q[32];
  {
    const short8v* vp = (const short8v*)(qkv + base);
#pragma unroll
    for (int c8 = 0; c8 < 4; ++c8) {
      short8v v = vp[c8];
#pragma unroll
      for (int e = 0; e < 8; ++e) q[c8 * 8 + e] = bf2f((unsigned short)v[e]);
    }
  }

  float logit[9];
#pragma unroll
  for (int ti = 0; ti < 3; ++ti)
#pragma unroll
    for (int tj = 0; tj < 3; ++tj) {
      const int t = ti * 3 + tj;
      const int hn = h + (ti - 1) * dil, wn = w + (tj - 1) * dil;
      if ((unsigned)hn < 56u && (unsigned)wn < 56u) {
        const int nb = n + (ti - 1) * dil * W_ + (tj - 1) * dil;
        const short8v* kp = (const short8v*)(qkv + (size_t)nb * C3_ + C_ + (size_t)r * HD_);
        float dot = 0.f;
#pragma unroll
        for (int c8 = 0; c8 < 4; ++c8) {
          short8v v = kp[c8];
#pragma unroll
          for (int e = 0; e < 8; ++e) dot += q[c8 * 8 + e] * bf2f((unsigned short)v[e]);
        }
        logit[t] = dot * 0.17677669529663688f;  // 32^-0.5
      } else {
        logit[t] = 0.f;  // zero-padded taps participate with logit 0
      }
    }

  float mx = logit[0];
#pragma unroll
  for (int t = 1; t < 9; ++t) mx = fmaxf(mx, logit[t]);
  float wgt[9]; float se = 0.f;
#pragma unroll
  for (int t = 0; t < 9; ++t) { wgt[t] = __expf(logit[t] - mx); se += wgt[t]; }
  const float inv = 1.f / se;

  float acc[32];
#pragma unroll
  for (int c = 0; c < 32; ++c) acc[c] = 0.f;
#pragma unroll
  for (int ti = 0; ti < 3; ++ti)
#pragma unroll
    for (int tj = 0; tj < 3; ++tj) {
      const int t = ti * 3 + tj;
      const int hn = h + (ti - 1) * dil, wn = w + (tj - 1) * dil;
      if ((unsigned)hn < 56u && (unsigned)wn < 56u) {
        const int nb = n + (ti - 1) * dil * W_ + (tj - 1) * dil;
        const short8v* vp = (const short8v*)(qkv + (size_t)nb * C3_ + 2 * C_ + (size_t)r * HD_);
        const float wt = wgt[t];
#pragma unroll
        for (int c8 = 0; c8 < 4; ++c8) {
          short8v v = vp[c8];
#pragma unroll
          for (int e = 0; e < 8; ++e) acc[c8 * 8 + e] += wt * bf2f((unsigned short)v[e]);
        }
      }
    }

  const size_t obase = (size_t)n * C_ + (size_t)r * HD_;
  const short8v* xv = (const short8v*)(xn + obase);
  short8v ov[4];
#pragma unroll
  for (int c8 = 0; c8 < 4; ++c8) {
    short8v v = xv[c8];
#pragma unroll
    for (int e = 0; e < 8; ++e)
      ov[c8][e] = (short)f2bf(acc[c8 * 8 + e] * inv + bf2f((unsigned short)v[e]));
  }
  short8v* op = (short8v*)(aout + obase);
#pragma unroll
  for (int c8 = 0; c8 < 4; ++c8) op[c8] = ov[c8];
}

extern "C" void kernel_launch(void* const* d_in, const int* in_sizes, int n_in,
                              void* d_out, int out_size, void* d_ws, size_t ws_size,
                              hipStream_t stream) {
  const float* x = (const float*)d_in[0];
  const float* qkv_w = (const float*)d_in[1];
  const float* proj_w = (const float*)d_in[2];
  const float* proj_b = (const float*)d_in[3];
  const float* n1_g = (const float*)d_in[4];
  const float* n1_b = (const float*)d_in[5];
  const float* n2_g = (const float*)d_in[6];
  const float* n2_b = (const float*)d_in[7];
  const float* fc1_w = (const float*)d_in[8];
  const float* fc1_b = (const float*)d_in[9];
  const float* fc2_w = (const float*)d_in[10];
  const float* fc2_b = (const float*)d_in[11];

  char* ws = (char*)d_ws;
  float* xp = (float*)ws;                                        // [N,C] f32
  unsigned short* xn = (unsigned short*)(ws + 38535168);         // [N,C] bf16
  unsigned short* qkvb = (unsigned short*)(ws + 57802752);       // [N,1152] bf16
  unsigned short* abuf = (unsigned short*)(ws + 115605504);      // [N,C] bf16
  unsigned short* hbuf = qkvb;                                   // [N,1536] bf16 (reuse qkv+abuf)
  unsigned short* wq = (unsigned short*)(ws + 134873088);
  unsigned short* wp = wq + 442368;
  unsigned short* wf1 = wp + 147456;
  unsigned short* wf2 = wf1 + 589824;

  cvt_weights<<<6912, 256, 0, stream>>>(qkv_w, proj_w, fc1_w, fc2_w, wq);
  transpose_in<<<dim3(98, 12, 8), dim3(32, 8), 0, stream>>>(x, xp);
  ln_rows<<<6272, 256, 0, stream>>>(xp, xn, n1_g, n1_b);
  // grid: x = n-tiles (fast -> same A-panel adjacent in dispatch), y = m-tiles
  gemm128<0><<<dim3(9, 196), 512, 0, stream>>>(xn, wq, nullptr, nullptr, qkvb, C3_, C_);
  attn_kernel<<<1176, 256, 0, stream>>>(qkvb, xn, abuf);
  gemm128<1><<<dim3(3, 196), 512, 0, stream>>>(abuf, wp, proj_b, xp, xp, C_, C_);
  ln_rows<<<6272, 256, 0, stream>>>(xp, xn, n2_g, n2_b);
  gemm128<2><<<dim3(12, 196), 512, 0, stream>>>(xn, wf1, fc1_b, nullptr, hbuf, HID_, C_);
  gemm128<3><<<dim3(3, 196), 512, 0, stream>>>(hbuf, wf2, fc2_b, xp, d_out, C_, HID_);
}